// Round 10
// baseline (673.896 us; speedup 1.0000x reference)
//
#include <hip/hip_runtime.h>

#define BLK 128          // 2 waves; each wave owns 64 rows (2 row-tiles of 32)

typedef unsigned short u16;
typedef __attribute__((ext_vector_type(8)))  short bf16x8;
typedef __attribute__((ext_vector_type(8)))  unsigned short u16x8;
typedef __attribute__((ext_vector_type(4)))  unsigned short u16x4;
typedef __attribute__((ext_vector_type(4)))  float f32x4;
typedef __attribute__((ext_vector_type(16))) float f32x16;
typedef __attribute__((ext_vector_type(4)))  unsigned int u32x4;

struct KArgs { const void* p[29]; void* out; };

__device__ __forceinline__ float b2f(u16 u) { return __uint_as_float(((unsigned)u) << 16); }
__device__ __forceinline__ u16 f2b(float f) {
    unsigned x = __float_as_uint(f);
    return (u16)((x + 0x7FFFu + ((x >> 16) & 1u)) >> 16);   // RNE
}

// ---- epilogue chunk descriptors (verified; chunk20 = action_emb[col 32])
__device__ __constant__ unsigned char EP_KIND[31] = {
    0,0,0,0,0,0,0,0,0,0,0,0, 1,1,1,1, 0,0,0, 1, 0,0,0,0,0, 1,1,1,1,1,1 };
__device__ __constant__ unsigned char EP_P1[31] = {
    40,19,38,38,38,38,38,19,19,19,19,19, 0,2,3,5, 19,26,52, 1, 26,19,52,45,19, 4,4,4,4,4,4 };
__device__ __constant__ unsigned char EP_P2[31] = {
    18,20,22,23,24,25,26,27,28,29,30,31, 40,41,42,43, 35,36,37, 39, 32,33,34,19,38, 44,45,46,47,48,49 };

// ---- fragment-ordered weight arena: VERBATIM R5 (10 logical layers, hb L1 split 3+2).
// Fragment f, lane l, elem j at arena[f*512 + l*8 + j];
// value = W[perm(k)*N + NOFF + 32t + (l&31)], k = kk*16 + (l>>5)*8 + j, f = F0 + kk*NT + t.
// perm = swap k bits 2<->3 for layers consuming D-packed activations (all but first two).
__device__ __constant__ int P2_K[10]    = {64,80,64,80,64,80,144,144,144,64};
__device__ __constant__ int P2_NT[10]   = {2,3,2,3,2,3,3,2,2,2};
__device__ __constant__ int P2_N[10]    = {64,80,64,80,64,80,144,144,64,64};
__device__ __constant__ int P2_NOFF[10] = {0,0,0,0,0,0,0,96,0,0};
__device__ __constant__ int P2_WOFF[10] = {0,4096,11776,15872,23552,27648,35328,49152,58368,67584};
__device__ __constant__ int P2_BOFF[10] = {0,64,160,224,320,384,480,576,640,704};
__device__ __constant__ int P2_WIDX[10] = {3,9,5,11,7,13,15,15,17,19};
__device__ __constant__ int P2_PERM[10] = {0,0,1,1,1,1,1,1,1,1};
#define BIAS_BYTE_OFF 155648          // arena = 140*512 u16 = 143360 B < this; 16B aligned

__device__ __forceinline__ bool probe_f32(const void* st) {
    const u16* p = (const u16*)st;
    unsigned o = 0;
    #pragma unroll
    for (int j = 1; j <= 16; j++) o |= p[100 * j];
    return o == 0;                    // f32 layout: low16 of integral floats are 0
}

__global__ void poker_prep(KArgs a, u16* arena, float* biasar)
{
    const bool F32 = probe_f32(a.p[0]);
    const int L = blockIdx.x;
    const int K = P2_K[L], NT = P2_NT[L], N = P2_N[L], NO = P2_NOFF[L], PM = P2_PERM[L];
    const void* W = a.p[P2_WIDX[L]];
    const void* b = a.p[P2_WIDX[L] + 1];
    u16* wt = arena + P2_WOFF[L];
    const int total = NT * K * 32;    // u16 elems
    for (int e = threadIdx.x; e < total; e += blockDim.x) {
        int f = e >> 3, j = e & 7;
        int l = f & 63, fi = f >> 6;
        int kk = fi / NT, t = fi - kk * NT;
        int n = NO + 32 * t + (l & 31);
        int k = kk * 16 + ((l >> 5) << 3) + j;
        int ks = PM ? ((k & ~12) | ((k & 4) << 1) | ((k & 8) >> 1)) : k;  // swap bits 2<->3
        float v = 0.f;
        if (n < N)
            v = F32 ? ((const float*)W)[ks * N + n] : b2f(((const u16*)W)[ks * N + n]);
        wt[e] = f2b(v);
    }
    const int BN = NT * 32;
    if ((int)threadIdx.x < BN) {
        int n = NO + threadIdx.x;
        float v = (n < N)
            ? (F32 ? ((const float*)b)[n] : b2f(((const u16*)b)[n]))
            : 0.f;
        biasar[P2_BOFF[L] + threadIdx.x] = v;
    }
}

// layer epilogue: bias + leaky-relu + RNE pack into D-pack order (R5-verbatim)
template<int NT, int NCO, bool ACT>
__device__ __forceinline__ void epi(const f32x16* acc, const float* __restrict__ sb,
                                    bf16x8* __restrict__ y, int h)
{
    #pragma unroll
    for (int t = 0; t < NT; t++) {
        #pragma unroll
        for (int s = 0; s < 2; s++) {
            if (2 * t + s < NCO) {
                unsigned w[4];
                #pragma unroll
                for (int gg = 0; gg < 2; gg++) {
                    const int G = 2 * s + gg;
                    f32x4 bv = *(const f32x4*)(sb + t * 32 + 8 * G + 4 * h);
                    float v0 = acc[t][4 * G + 0] + bv[0];
                    float v1 = acc[t][4 * G + 1] + bv[1];
                    float v2 = acc[t][4 * G + 2] + bv[2];
                    float v3 = acc[t][4 * G + 3] + bv[3];
                    if (ACT) {
                        v0 = fmaxf(v0, 0.01f * v0); v1 = fmaxf(v1, 0.01f * v1);
                        v2 = fmaxf(v2, 0.01f * v2); v3 = fmaxf(v3, 0.01f * v3);
                    }
                    w[2 * gg + 0] = (unsigned)f2b(v0) | ((unsigned)f2b(v1) << 16);
                    w[2 * gg + 1] = (unsigned)f2b(v2) | ((unsigned)f2b(v3) << 16);
                }
                u32x4 fw = { w[0], w[1], w[2], w[3] };
                y[2 * t + s] = __builtin_bit_cast(bf16x8, fw);
            }
        }
    }
}

// One layer for TWO row-tiles: each weight fragment loaded once, feeds 2 MFMAs.
// Fragment sequence and all math identical to R5's layerQ.
template<int F0, int K, int NT, int NCO, bool ACT>
__device__ __forceinline__ void layer2(
    const u16* __restrict__ arena, const float* __restrict__ sb,
    const bf16x8* __restrict__ x0, const bf16x8* __restrict__ x1,
    bf16x8* __restrict__ y0, bf16x8* __restrict__ y1, int lane)
{
    const int h = lane >> 5;
    f32x16 a0[NT] = {}, a1[NT] = {};
    #pragma unroll
    for (int kk = 0; kk < K / 16; kk++) {
        #pragma unroll
        for (int t = 0; t < NT; t++) {
            const int f = F0 + kk * NT + t;
            bf16x8 w = *(const bf16x8*)(arena + f * 512 + lane * 8);
            a0[t] = __builtin_amdgcn_mfma_f32_32x32x16_bf16(w, x0[kk], a0[t], 0, 0, 0);
            a1[t] = __builtin_amdgcn_mfma_f32_32x32x16_bf16(w, x1[kk], a1[t], 0, 0, 0);
        }
    }
    epi<NT, NCO, ACT>(a0, sb, y0, h);
    epi<NT, NCO, ACT>(a1, sb, y1, h);
}

template<bool F32>
__device__ void body(
    const KArgs& a, const u16* __restrict__ arena,
    u16* s_emb, float* s_scalW, float* s_scalB, float* sb,
    u16* ss16 /*wave's 64x50 bf16 state (bf16 path)*/,
    u16* hbp  /*wave's 64x72 HB de-swizzle*/,
    int lane, int wave, long row0)
{
    const int rbase = wave * 64;
    const int h = lane >> 5, r = lane & 31;
    const long rw0 = row0 + rbase;

    // ---- state staging: bf16 path stages 64 rows x 100B as raw u16 (dense copy);
    //      f32 path reads global directly (correctness-only: live inputs are bf16).
    if constexpr (!F32) {
        const char* gb = (const char*)a.p[0] + rw0 * 100;
        #pragma unroll
        for (int i = 0; i < 13; i++) {
            int uo = i * 512 + lane * 8;          // bytes into 6400B block
            if (uo < 6400)
                *(u16x4*)((char*)ss16 + uo) = *(const u16x4*)(gb + uo);
        }
    }

    // ---- card gather -> register fragments, both row-tiles (natural k order)
    bf16x8 xh0[4], xb0[5], xh1[4], xb1[5];
    #pragma unroll
    for (int c = 0; c < 9; c++) {
        float fv0, fv1;
        if constexpr (F32) {
            fv0 = ((const float*)a.p[0])[(rw0 + r) * 50 + 2 * c + 1 - h];
            fv1 = ((const float*)a.p[0])[(rw0 + r + 32) * 50 + 2 * c + 1 - h];
        } else {
            fv0 = b2f(ss16[r * 50 + 2 * c + 1 - h]);
            fv1 = b2f(ss16[(r + 32) * 50 + 2 * c + 1 - h]);
        }
        int i0 = (int)(fv0 + 0.5f);
        int i1 = (int)(fv1 + 0.5f);
        bf16x8 e0 = *(const bf16x8*)&s_emb[(h ? 5 + i0 : i0) * 8];
        bf16x8 e1 = *(const bf16x8*)&s_emb[(h ? 5 + i1 : i1) * 8];
        if (c < 4) { xh0[c] = e0; xh1[c] = e1; }
        else       { xb0[c - 4] = e0; xb1[c - 4] = e1; }
    }

    // ---- 10 layer segments (R5-verbatim frag stream: 0,8,23,31,46,54,69,96,114,132)
    bf16x8 h1_0[4], h1_1[4], b1_0[5], b1_1[5];
    layer2<  0,  64, 2, 4, true >(arena, sb + 0,   xh0, xh1, h1_0, h1_1, lane);
    layer2<  8,  80, 3, 5, true >(arena, sb + 64,  xb0, xb1, b1_0, b1_1, lane);
    bf16x8 h2_0[4], h2_1[4], b2_0[5], b2_1[5];
    layer2< 23,  64, 2, 4, true >(arena, sb + 160, h1_0, h1_1, h2_0, h2_1, lane);
    layer2< 31,  80, 3, 5, true >(arena, sb + 224, b1_0, b1_1, b2_0, b2_1, lane);
    bf16x8 hb0[9], hb1[9];
    layer2< 46,  64, 2, 4, false>(arena, sb + 320, h2_0, h2_1, hb0, hb1, lane);
    layer2< 54,  80, 3, 5, false>(arena, sb + 384, b2_0, b2_1, hb0 + 4, hb1 + 4, lane);
    bf16x8 c1_0[9], c1_1[9];
    layer2< 69, 144, 3, 6, true >(arena, sb + 480, hb0, hb1, c1_0, c1_1, lane);
    layer2< 96, 144, 2, 3, true >(arena, sb + 576, hb0, hb1, c1_0 + 6, c1_1 + 6, lane);
    bf16x8 c2_0[4], c2_1[4];
    layer2<114, 144, 2, 4, true >(arena, sb + 640, c1_0, c1_1, c2_0, c2_1, lane);
    bf16x8 c3_0[4], c3_1[4];
    layer2<132,  64, 2, 4, false>(arena, sb + 704, c2_0, c2_1, c3_0, c3_1, lane);

    // ---- de-swizzle final 64 feats, both tiles (R5-verbatim mapping)
    // c3[c][e] = feature 16c + 8*(e>>2) + 4h + (e&3)
    #pragma unroll
    for (int c = 0; c < 4; c++) {
        u16x4 lo0 = { (u16)c3_0[c][0], (u16)c3_0[c][1], (u16)c3_0[c][2], (u16)c3_0[c][3] };
        u16x4 hi0 = { (u16)c3_0[c][4], (u16)c3_0[c][5], (u16)c3_0[c][6], (u16)c3_0[c][7] };
        *(u16x4*)&hbp[r * 72 + c * 16 + 4 * h]     = lo0;
        *(u16x4*)&hbp[r * 72 + c * 16 + 8 + 4 * h] = hi0;
        u16x4 lo1 = { (u16)c3_1[c][0], (u16)c3_1[c][1], (u16)c3_1[c][2], (u16)c3_1[c][3] };
        u16x4 hi1 = { (u16)c3_1[c][4], (u16)c3_1[c][5], (u16)c3_1[c][6], (u16)c3_1[c][7] };
        *(u16x4*)&hbp[(r + 32) * 72 + c * 16 + 4 * h]     = lo1;
        *(u16x4*)&hbp[(r + 32) * 72 + c * 16 + 8 + 4 * h] = hi1;
    }

    // ---- final epilogue: 64 rows x 39 chunks (R5-verbatim logic, extended extent)
    if constexpr (F32) {
        float* obase = (float*)a.out + rw0 * 312;
        const int hf = lane & 1, ql = lane >> 1;
        for (int i = 0; i < 78; i++) {
            int q = 32 * i + ql;                  // 0..2495, exact
            int r2 = q / 39, c = q - 39 * r2;
            f32x4 ov;
            if (c < 8) {
                u16x4 w = *(const u16x4*)&hbp[r2 * 72 + c * 8 + hf * 4];
                ov[0] = b2f(w[0]); ov[1] = b2f(w[1]); ov[2] = b2f(w[2]); ov[3] = b2f(w[3]);
            } else {
                int e = c - 8;
                int col = EP_P2[e], p1 = EP_P1[e];
                float sv = ((const float*)a.p[0])[(rw0 + r2) * 50 + col];
                if (EP_KIND[e] == 0) {
                    int idx = (int)(sv + 0.5f);
                    u16x4 w = *(const u16x4*)&s_emb[(p1 + idx) * 8 + hf * 4];
                    ov[0] = b2f(w[0]); ov[1] = b2f(w[1]); ov[2] = b2f(w[2]); ov[3] = b2f(w[3]);
                } else {
                    #pragma unroll
                    for (int j = 0; j < 4; j++)
                        ov[j] = fmaf(sv, s_scalW[p1 * 8 + hf * 4 + j], s_scalB[p1 * 8 + hf * 4 + j]);
                }
            }
            *(f32x4*)(obase + i * 256 + lane * 4) = ov;    // dense 1KB wave store
        }
    } else {
        for (int i = 0; i < 39; i++) {
            int u = lane + 64 * i;                // 0..2495, exact
            int r2 = u / 39, c = u - 39 * r2;
            float v[8];
            if (c < 8) {
                u16x8 w = *(const u16x8*)&hbp[r2 * 72 + c * 8];
                #pragma unroll
                for (int j = 0; j < 8; j++) v[j] = b2f(w[j]);
            } else {
                int e = c - 8;
                int col = EP_P2[e], p1 = EP_P1[e];
                float sv = b2f(ss16[r2 * 50 + col]);
                if (EP_KIND[e] == 0) {
                    int idx = (int)(sv + 0.5f);
                    u16x8 w = *(const u16x8*)&s_emb[(p1 + idx) * 8];
                    #pragma unroll
                    for (int j = 0; j < 8; j++) v[j] = b2f(w[j]);
                } else {
                    #pragma unroll
                    for (int j = 0; j < 8; j++)
                        v[j] = fmaf(sv, s_scalW[p1 * 8 + j], s_scalB[p1 * 8 + j]);
                }
            }
            u16x8 w;
            #pragma unroll
            for (int j = 0; j < 8; j++) w[j] = f2b(v[j]);
            *(u16x8*)&((u16*)a.out)[(rw0 + r2) * 312 + c * 8] = w;
        }
    }
}

__global__ __launch_bounds__(BLK, 2) void poker_main(
    KArgs a, const u16* __restrict__ arena, const float* __restrict__ biasar)
{
    __shared__ alignas(16) u16   s_st16[2][64 * 50];   // 12.8KB (bf16-path state)
    __shared__ alignas(16) u16   s_HB[2][64 * 72];     // 18.4KB
    __shared__ alignas(16) float s_bias[768];          // 3KB
    __shared__ alignas(16) u16   s_emb[54 * 8];
    __shared__ alignas(16) float s_scalW[48];
    __shared__ alignas(16) float s_scalB[48];

    const int tid = threadIdx.x;
    const int lane = tid & 63, wave = tid >> 6;
    const long row0 = (long)blockIdx.x * 128;
    const bool isf32 = probe_f32(a.p[0]);

    // ---- block-wide staging of tiny tables (the only barrier in the kernel)
    {
        const void* srcs[8] = { a.p[1], a.p[2], a.p[21], a.p[22], a.p[23], a.p[24], a.p[25], a.p[26] };
        const int  cnt[8]   = { 5, 14, 7, 12, 2, 5, 7, 2 };
        int base = 0;
        for (int t = 0; t < 8; t++) {
            int n = cnt[t] * 8;
            for (int i = tid; i < n; i += BLK)
                s_emb[base + i] = isf32 ? f2b(((const float*)srcs[t])[i]) : ((const u16*)srcs[t])[i];
            base += n;
        }
        if (tid < 48) {
            s_scalW[tid] = isf32 ? ((const float*)a.p[27])[tid] : b2f(((const u16*)a.p[27])[tid]);
            s_scalB[tid] = isf32 ? ((const float*)a.p[28])[tid] : b2f(((const u16*)a.p[28])[tid]);
        }
        for (int i = tid; i < 192; i += BLK)
            ((f32x4*)s_bias)[i] = ((const f32x4*)biasar)[i];
    }
    __syncthreads();

    u16* ss16 = &s_st16[wave][0];
    u16* hbp  = &s_HB[wave][0];
    if (isf32) body<true >(a, arena, s_emb, s_scalW, s_scalB, s_bias, ss16, hbp, lane, wave, row0);
    else       body<false>(a, arena, s_emb, s_scalW, s_scalB, s_bias, ss16, hbp, lane, wave, row0);
}

extern "C" void kernel_launch(void* const* d_in, const int* in_sizes, int n_in,
                              void* d_out, int out_size, void* d_ws, size_t ws_size,
                              hipStream_t stream) {
    KArgs args;
    for (int i = 0; i < 29; i++) args.p[i] = d_in[i];
    args.out = d_out;
    u16*   arena  = (u16*)d_ws;
    float* biasar = (float*)((char*)d_ws + BIAS_BYTE_OFF);
    int rows = in_sizes[0] / 50;          // 262144
    int blocks = rows / 128;              // 2048

    poker_prep<<<dim3(10), dim3(256), 0, stream>>>(args, arena, biasar);
    poker_main<<<dim3(blocks), dim3(BLK), 0, stream>>>(args, arena, biasar);
}